// Round 1
// baseline (61.328 us; speedup 1.0000x reference)
//
#include <hip/hip_runtime.h>

#define B_ 8
#define T_ 2048
#define V_ 256
#define D_ 512
#define LEFT_ 16
#define BT 16                      // tokens per block
#define NROWS (BT + LEFT_ - 1)     // 31 staged rows

__global__ __launch_bounds__(256, 2)
void attn_cell_kernel(const int* __restrict__ symbols,
                      const float* __restrict__ encodings,
                      const float* __restrict__ M,
                      const float* __restrict__ C,
                      float* __restrict__ out,      // (B,T,1024)
                      float* __restrict__ p_out) {  // (B,T,16)
    __shared__ float rows[NROWS][D_];   // 62 KB, reused for M then C
    __shared__ int sym_s[NROWS];

    const int tid  = threadIdx.x;
    const int lane = tid & 63;
    const int w    = tid >> 6;

    const int blk = blockIdx.x;
    const int b   = blk / (T_ / BT);
    const int t0  = (blk % (T_ / BT)) * BT;

    // symbols for context positions t0-15 .. t0+BT-1 (pad with symbols[b,0])
    if (tid < NROWS) {
        int pos = t0 - (LEFT_ - 1) + tid;
        if (pos < 0) pos = 0;
        sym_s[tid] = symbols[b * T_ + pos];
    }
    __syncthreads();

    // ---- stage M rows into LDS ----
    for (int i = tid; i < NROWS * (D_ / 4); i += 256) {
        const int r = i >> 7;       // /128
        const int c = i & 127;
        const float4 v = reinterpret_cast<const float4*>(M + (size_t)sym_s[r] * D_)[c];
        reinterpret_cast<float4*>(&rows[r][0])[c] = v;
    }
    __syncthreads();

    float p_reg[4][16];             // p for this wave's 4 tokens, all lanes identical

    // ---- phase 1: scores + softmax + enc copy ----
    #pragma unroll
    for (int i = 0; i < 4; ++i) {
        const int lt = w + i * 4;
        const int t  = t0 + lt;
        const size_t ebase = ((size_t)(b * T_ + t)) * D_ + (size_t)lane * 8;
        const float4 e0 = *reinterpret_cast<const float4*>(encodings + ebase);
        const float4 e1 = *reinterpret_cast<const float4*>(encodings + ebase + 4);

        float s[16];
        #pragma unroll
        for (int l = 0; l < 16; ++l) {
            const float* rp = &rows[lt + l][lane * 8];
            const float4 m0 = *reinterpret_cast<const float4*>(rp);
            const float4 m1 = *reinterpret_cast<const float4*>(rp + 4);
            s[l] = m0.x * e0.x + m0.y * e0.y + m0.z * e0.z + m0.w * e0.w
                 + m1.x * e1.x + m1.y * e1.y + m1.z * e1.z + m1.w * e1.w;
        }
        // butterfly reduce all 16 partials across the 64-lane wave
        #pragma unroll
        for (int off = 1; off < 64; off <<= 1) {
            #pragma unroll
            for (int l = 0; l < 16; ++l) s[l] += __shfl_xor(s[l], off);
        }
        // softmax (redundant in every lane — cheap, keeps p in registers)
        float mx = s[0];
        #pragma unroll
        for (int l = 1; l < 16; ++l) mx = fmaxf(mx, s[l]);
        float sum = 0.f;
        #pragma unroll
        for (int l = 0; l < 16; ++l) { s[l] = __expf(s[l] - mx); sum += s[l]; }
        const float inv = 1.f / sum;
        #pragma unroll
        for (int l = 0; l < 16; ++l) p_reg[i][l] = s[l] * inv;

        if (lane == 0) {
            float4* pp = reinterpret_cast<float4*>(p_out + ((size_t)(b * T_ + t)) * 16);
            pp[0] = make_float4(p_reg[i][0],  p_reg[i][1],  p_reg[i][2],  p_reg[i][3]);
            pp[1] = make_float4(p_reg[i][4],  p_reg[i][5],  p_reg[i][6],  p_reg[i][7]);
            pp[2] = make_float4(p_reg[i][8],  p_reg[i][9],  p_reg[i][10], p_reg[i][11]);
            pp[3] = make_float4(p_reg[i][12], p_reg[i][13], p_reg[i][14], p_reg[i][15]);
        }
        // encoding passthrough: out[b,t,512:1024] = enc
        float4* ob = reinterpret_cast<float4*>(out + ((size_t)(b * T_ + t)) * 1024 + D_ + (size_t)lane * 8);
        ob[0] = e0; ob[1] = e1;
    }
    __syncthreads();

    // ---- stage C rows into the same LDS ----
    for (int i = tid; i < NROWS * (D_ / 4); i += 256) {
        const int r = i >> 7;
        const int c = i & 127;
        const float4 v = reinterpret_cast<const float4*>(C + (size_t)sym_s[r] * D_)[c];
        reinterpret_cast<float4*>(&rows[r][0])[c] = v;
    }
    __syncthreads();

    // ---- phase 2: compressed = sum_l p_l * C_row_l ----
    #pragma unroll
    for (int i = 0; i < 4; ++i) {
        const int lt = w + i * 4;
        const int t  = t0 + lt;
        float4 a0 = make_float4(0.f, 0.f, 0.f, 0.f);
        float4 a1 = make_float4(0.f, 0.f, 0.f, 0.f);
        #pragma unroll
        for (int l = 0; l < 16; ++l) {
            const float* rp = &rows[lt + l][lane * 8];
            const float4 c0 = *reinterpret_cast<const float4*>(rp);
            const float4 c1 = *reinterpret_cast<const float4*>(rp + 4);
            const float pl = p_reg[i][l];
            a0.x += pl * c0.x; a0.y += pl * c0.y; a0.z += pl * c0.z; a0.w += pl * c0.w;
            a1.x += pl * c1.x; a1.y += pl * c1.y; a1.z += pl * c1.z; a1.w += pl * c1.w;
        }
        float4* ob = reinterpret_cast<float4*>(out + ((size_t)(b * T_ + t)) * 1024 + (size_t)lane * 8);
        ob[0] = a0; ob[1] = a1;
    }
}

extern "C" void kernel_launch(void* const* d_in, const int* in_sizes, int n_in,
                              void* d_out, int out_size, void* d_ws, size_t ws_size,
                              hipStream_t stream) {
    const int*   symbols   = (const int*)d_in[0];
    const float* encodings = (const float*)d_in[1];
    const float* M         = (const float*)d_in[2];
    const float* C         = (const float*)d_in[3];
    float* out   = (float*)d_out;
    float* p_out = out + (size_t)B_ * T_ * 1024;   // concat order: output, then p

    dim3 grid(B_ * (T_ / BT));
    attn_cell_kernel<<<grid, 256, 0, stream>>>(symbols, encodings, M, C, out, p_out);
}

// Round 2
// 56.119 us; speedup vs baseline: 1.0928x; 1.0928x over previous
//
#include <hip/hip_runtime.h>
#include <hip/hip_bf16.h>

#define B_ 8
#define T_ 2048
#define V_ 256
#define D_ 512
#define LEFT_ 16
#define BT 16                      // tokens per block
#define NROWS (BT + LEFT_ - 1)     // 31 staged rows

// bf16 pair (packed in uint) -> two floats
__device__ __forceinline__ float bf_lo(unsigned u) {
    union { unsigned u; float f; } c; c.u = u << 16; return c.f;
}
__device__ __forceinline__ float bf_hi(unsigned u) {
    union { unsigned u; float f; } c; c.u = u & 0xffff0000u; return c.f;
}
__device__ __forceinline__ unsigned pack_bf2(float a, float b) {
    __hip_bfloat162 h = __float22bfloat162_rn(make_float2(a, b));
    union { __hip_bfloat162 h; unsigned u; } c; c.h = h; return c.u;
}

__global__ __launch_bounds__(256, 4)
void attn_cell_kernel(const int* __restrict__ symbols,
                      const float* __restrict__ encodings,
                      const float* __restrict__ M,
                      const float* __restrict__ C,
                      float* __restrict__ out,      // (B,T,1024)
                      float* __restrict__ p_out) {  // (B,T,16)
    // rows in bf16, 2 elems per uint: 31 rows x 256 uints = 31 KB
    __shared__ __align__(16) unsigned rows[NROWS][D_ / 2];
    __shared__ int sym_s[NROWS];

    const int tid  = threadIdx.x;
    const int lane = tid & 63;
    const int w    = tid >> 6;

    const int blk = blockIdx.x;
    const int b   = blk / (T_ / BT);
    const int t0  = (blk % (T_ / BT)) * BT;

    if (tid < NROWS) {
        int pos = t0 - (LEFT_ - 1) + tid;
        if (pos < 0) pos = 0;
        sym_s[tid] = symbols[b * T_ + pos];
    }
    __syncthreads();

    // ---- stage M rows into LDS (f32 -> bf16) ----
    for (int i = tid; i < NROWS * (D_ / 4); i += 256) {
        const int r = i >> 7;       // /128 float4-granules per row
        const int c = i & 127;
        const float4 v = reinterpret_cast<const float4*>(M + (size_t)sym_s[r] * D_)[c];
        uint2 pkd = make_uint2(pack_bf2(v.x, v.y), pack_bf2(v.z, v.w));
        *reinterpret_cast<uint2*>(&rows[r][c * 2]) = pkd;
    }
    __syncthreads();

    float p_reg[4][16];             // p for this wave's 4 tokens (all lanes hold all 16)

    // ---- phase 1: scores + softmax + enc passthrough ----
    #pragma unroll
    for (int i = 0; i < 4; ++i) {
        const int lt = w + i * 4;
        const int t  = t0 + lt;
        const size_t ebase = ((size_t)(b * T_ + t)) * D_ + (size_t)lane * 8;
        const float4 e0 = *reinterpret_cast<const float4*>(encodings + ebase);
        const float4 e1 = *reinterpret_cast<const float4*>(encodings + ebase + 4);

        float s[16];
        #pragma unroll
        for (int l = 0; l < 16; ++l) {
            // lane reads 16B: 8 bf16 elems at rows[lt+l][lane*4 .. lane*4+3]
            const uint4 m = *reinterpret_cast<const uint4*>(&rows[lt + l][lane * 4]);
            s[l] = bf_lo(m.x) * e0.x + bf_hi(m.x) * e0.y
                 + bf_lo(m.y) * e0.z + bf_hi(m.y) * e0.w
                 + bf_lo(m.z) * e1.x + bf_hi(m.z) * e1.y
                 + bf_lo(m.w) * e1.z + bf_hi(m.w) * e1.w;
        }
        #pragma unroll
        for (int off = 1; off < 64; off <<= 1) {
            #pragma unroll
            for (int l = 0; l < 16; ++l) s[l] += __shfl_xor(s[l], off);
        }
        float mx = s[0];
        #pragma unroll
        for (int l = 1; l < 16; ++l) mx = fmaxf(mx, s[l]);
        float sum = 0.f;
        #pragma unroll
        for (int l = 0; l < 16; ++l) { s[l] = __expf(s[l] - mx); sum += s[l]; }
        const float inv = 1.f / sum;
        #pragma unroll
        for (int l = 0; l < 16; ++l) p_reg[i][l] = s[l] * inv;

        if (lane == 0) {
            float4* pp = reinterpret_cast<float4*>(p_out + ((size_t)(b * T_ + t)) * 16);
            pp[0] = make_float4(p_reg[i][0],  p_reg[i][1],  p_reg[i][2],  p_reg[i][3]);
            pp[1] = make_float4(p_reg[i][4],  p_reg[i][5],  p_reg[i][6],  p_reg[i][7]);
            pp[2] = make_float4(p_reg[i][8],  p_reg[i][9],  p_reg[i][10], p_reg[i][11]);
            pp[3] = make_float4(p_reg[i][12], p_reg[i][13], p_reg[i][14], p_reg[i][15]);
        }
        float4* ob = reinterpret_cast<float4*>(out + ((size_t)(b * T_ + t)) * 1024 + D_ + (size_t)lane * 8);
        ob[0] = e0; ob[1] = e1;
    }
    __syncthreads();

    // ---- stage C rows ----
    for (int i = tid; i < NROWS * (D_ / 4); i += 256) {
        const int r = i >> 7;
        const int c = i & 127;
        const float4 v = reinterpret_cast<const float4*>(C + (size_t)sym_s[r] * D_)[c];
        uint2 pkd = make_uint2(pack_bf2(v.x, v.y), pack_bf2(v.z, v.w));
        *reinterpret_cast<uint2*>(&rows[r][c * 2]) = pkd;
    }
    __syncthreads();

    // ---- phase 2: compressed = sum_l p_l * C_row_l ----
    #pragma unroll
    for (int i = 0; i < 4; ++i) {
        const int lt = w + i * 4;
        const int t  = t0 + lt;
        float4 a0 = make_float4(0.f, 0.f, 0.f, 0.f);
        float4 a1 = make_float4(0.f, 0.f, 0.f, 0.f);
        #pragma unroll
        for (int l = 0; l < 16; ++l) {
            const uint4 c4 = *reinterpret_cast<const uint4*>(&rows[lt + l][lane * 4]);
            const float pl = p_reg[i][l];
            a0.x += pl * bf_lo(c4.x); a0.y += pl * bf_hi(c4.x);
            a0.z += pl * bf_lo(c4.y); a0.w += pl * bf_hi(c4.y);
            a1.x += pl * bf_lo(c4.z); a1.y += pl * bf_hi(c4.z);
            a1.z += pl * bf_lo(c4.w); a1.w += pl * bf_hi(c4.w);
        }
        float4* ob = reinterpret_cast<float4*>(out + ((size_t)(b * T_ + t)) * 1024 + (size_t)lane * 8);
        ob[0] = a0; ob[1] = a1;
    }
}

extern "C" void kernel_launch(void* const* d_in, const int* in_sizes, int n_in,
                              void* d_out, int out_size, void* d_ws, size_t ws_size,
                              hipStream_t stream) {
    const int*   symbols   = (const int*)d_in[0];
    const float* encodings = (const float*)d_in[1];
    const float* M         = (const float*)d_in[2];
    const float* C         = (const float*)d_in[3];
    float* out   = (float*)d_out;
    float* p_out = out + (size_t)B_ * T_ * 1024;   // concat order: output, then p

    dim3 grid(B_ * (T_ / BT));
    attn_cell_kernel<<<grid, 256, 0, stream>>>(symbols, encodings, M, C, out, p_out);
}

// Round 3
// 37.234 us; speedup vs baseline: 1.6471x; 1.5072x over previous
//
#include <hip/hip_runtime.h>
#include <hip/hip_bf16.h>

#define B_ 8
#define T_ 2048
#define V_ 256
#define D_ 512
#define LEFT_ 16
#define BT 16                      // tokens per block
#define NROWS (BT + LEFT_ - 1)     // 31 staged rows

__device__ __forceinline__ float bf_lo(unsigned u) {
    union { unsigned u; float f; } c; c.u = u << 16; return c.f;
}
__device__ __forceinline__ float bf_hi(unsigned u) {
    union { unsigned u; float f; } c; c.u = u & 0xffff0000u; return c.f;
}
__device__ __forceinline__ unsigned pack_bf2(float a, float b) {
    __hip_bfloat162 h = __float22bfloat162_rn(make_float2(a, b));
    union { __hip_bfloat162 h; unsigned u; } c; c.h = h; return c.u;
}

__global__ __launch_bounds__(256, 4)
void attn_cell_kernel(const int* __restrict__ symbols,
                      const float* __restrict__ encodings,
                      const float* __restrict__ M,
                      const float* __restrict__ C,
                      float* __restrict__ out,      // (B,T,1024)
                      float* __restrict__ p_out) {  // (B,T,16)
    // rows in bf16 (2 elems per uint): 31 KB.  p_s: 1 KB.  Total = 32768 B exactly.
    __shared__ __align__(16) unsigned rows[NROWS][D_ / 2];
    __shared__ __align__(16) float p_s[BT][16];

    const int tid  = threadIdx.x;
    const int lane = tid & 63;
    const int w    = tid >> 6;

    const int blk = blockIdx.x;
    const int b   = blk / (T_ / BT);
    const int t0  = (blk % (T_ / BT)) * BT;
    const int* symrow = symbols + b * T_;

    // ---- stage M rows into LDS (f32 -> bf16); symbol fetched per-thread (L1-hot) ----
    for (int i = tid; i < NROWS * (D_ / 4); i += 256) {
        const int r = i >> 7;       // 128 float4-granules per row
        const int c = i & 127;
        int pos = t0 - (LEFT_ - 1) + r;
        if (pos < 0) pos = 0;
        const int sym = symrow[pos];
        const float4 v = reinterpret_cast<const float4*>(M + (size_t)sym * D_)[c];
        *reinterpret_cast<uint2*>(&rows[r][c * 2]) =
            make_uint2(pack_bf2(v.x, v.y), pack_bf2(v.z, v.w));
    }
    __syncthreads();

    // bit-reversed 4-bit lane id: the row index this lane ends up owning
    const int l4  = lane & 15;
    const int rl  = ((l4 & 1) << 3) | ((l4 & 2) << 1) | ((l4 & 4) >> 1) | ((l4 & 8) >> 3);

    // ---- phase 1: scores + folding reduce + group softmax + enc passthrough ----
    #pragma unroll
    for (int i = 0; i < 4; ++i) {
        const int lt = w + i * 4;
        const int t  = t0 + lt;
        const size_t ebase = ((size_t)(b * T_ + t)) * D_ + (size_t)lane * 8;
        const float4 e0 = *reinterpret_cast<const float4*>(encodings + ebase);
        const float4 e1 = *reinterpret_cast<const float4*>(encodings + ebase + 4);

        float s[16];
        #pragma unroll
        for (int l = 0; l < 16; ++l) {
            const uint4 m = *reinterpret_cast<const uint4*>(&rows[lt + l][lane * 4]);
            s[l] = bf_lo(m.x) * e0.x + bf_hi(m.x) * e0.y
                 + bf_lo(m.y) * e0.z + bf_hi(m.y) * e0.w
                 + bf_lo(m.z) * e1.x + bf_hi(m.z) * e1.y
                 + bf_lo(m.w) * e1.z + bf_hi(m.w) * e1.w;
        }

        // folding butterfly: 15 shfl, value count 16 -> 1
        #pragma unroll
        for (int k = 0; k < 8; ++k) {   // xor 1
            const float lo = s[k], hi = s[k + 8];
            const float sd = (lane & 1) ? lo : hi;
            const float rv = __shfl_xor(sd, 1);
            s[k] = (lane & 1) ? hi + rv : lo + rv;
        }
        #pragma unroll
        for (int k = 0; k < 4; ++k) {   // xor 2
            const float lo = s[k], hi = s[k + 4];
            const float sd = (lane & 2) ? lo : hi;
            const float rv = __shfl_xor(sd, 2);
            s[k] = (lane & 2) ? hi + rv : lo + rv;
        }
        #pragma unroll
        for (int k = 0; k < 2; ++k) {   // xor 4
            const float lo = s[k], hi = s[k + 2];
            const float sd = (lane & 4) ? lo : hi;
            const float rv = __shfl_xor(sd, 4);
            s[k] = (lane & 4) ? hi + rv : lo + rv;
        }
        {                               // xor 8
            const float lo = s[0], hi = s[1];
            const float sd = (lane & 8) ? lo : hi;
            const float rv = __shfl_xor(sd, 8);
            s[0] = (lane & 8) ? hi + rv : lo + rv;
        }
        float v = s[0];
        v += __shfl_xor(v, 16);
        v += __shfl_xor(v, 32);
        // lane now holds the full score for row rl of token t

        // group softmax across the 16-lane group
        float mx = v;
        mx = fmaxf(mx, __shfl_xor(mx, 1));
        mx = fmaxf(mx, __shfl_xor(mx, 2));
        mx = fmaxf(mx, __shfl_xor(mx, 4));
        mx = fmaxf(mx, __shfl_xor(mx, 8));
        const float e = __expf(v - mx);
        float sum = e;
        sum += __shfl_xor(sum, 1);
        sum += __shfl_xor(sum, 2);
        sum += __shfl_xor(sum, 4);
        sum += __shfl_xor(sum, 8);
        const float p = e / sum;

        if (lane < 16) {
            p_out[((size_t)(b * T_ + t)) * 16 + rl] = p;
            p_s[lt][rl] = p;
        }

        // enc passthrough: out[b,t,512:1024] = enc (exact f32)
        float4* ob = reinterpret_cast<float4*>(out + ((size_t)(b * T_ + t)) * 1024 + D_ + (size_t)lane * 8);
        ob[0] = e0; ob[1] = e1;
    }
    __syncthreads();

    // ---- stage C rows (reuse LDS) ----
    for (int i = tid; i < NROWS * (D_ / 4); i += 256) {
        const int r = i >> 7;
        const int c = i & 127;
        int pos = t0 - (LEFT_ - 1) + r;
        if (pos < 0) pos = 0;
        const int sym = symrow[pos];
        const float4 v = reinterpret_cast<const float4*>(C + (size_t)sym * D_)[c];
        *reinterpret_cast<uint2*>(&rows[r][c * 2]) =
            make_uint2(pack_bf2(v.x, v.y), pack_bf2(v.z, v.w));
    }
    __syncthreads();

    // ---- phase 2: compressed = sum_l p_l * C_row_l ----
    #pragma unroll
    for (int i = 0; i < 4; ++i) {
        const int lt = w + i * 4;
        const int t  = t0 + lt;
        // broadcast reads (uniform address): 4x ds_read_b128
        const float4 q0 = *reinterpret_cast<const float4*>(&p_s[lt][0]);
        const float4 q1 = *reinterpret_cast<const float4*>(&p_s[lt][4]);
        const float4 q2 = *reinterpret_cast<const float4*>(&p_s[lt][8]);
        const float4 q3 = *reinterpret_cast<const float4*>(&p_s[lt][12]);
        const float pw[16] = { q0.x, q0.y, q0.z, q0.w, q1.x, q1.y, q1.z, q1.w,
                               q2.x, q2.y, q2.z, q2.w, q3.x, q3.y, q3.z, q3.w };

        float4 a0 = make_float4(0.f, 0.f, 0.f, 0.f);
        float4 a1 = make_float4(0.f, 0.f, 0.f, 0.f);
        #pragma unroll
        for (int l = 0; l < 16; ++l) {
            const uint4 c4 = *reinterpret_cast<const uint4*>(&rows[lt + l][lane * 4]);
            const float pl = pw[l];
            a0.x += pl * bf_lo(c4.x); a0.y += pl * bf_hi(c4.x);
            a0.z += pl * bf_lo(c4.y); a0.w += pl * bf_hi(c4.y);
            a1.x += pl * bf_lo(c4.z); a1.y += pl * bf_hi(c4.z);
            a1.z += pl * bf_lo(c4.w); a1.w += pl * bf_hi(c4.w);
        }
        float4* ob = reinterpret_cast<float4*>(out + ((size_t)(b * T_ + t)) * 1024 + (size_t)lane * 8);
        ob[0] = a0; ob[1] = a1;
    }
}

extern "C" void kernel_launch(void* const* d_in, const int* in_sizes, int n_in,
                              void* d_out, int out_size, void* d_ws, size_t ws_size,
                              hipStream_t stream) {
    const int*   symbols   = (const int*)d_in[0];
    const float* encodings = (const float*)d_in[1];
    const float* M         = (const float*)d_in[2];
    const float* C         = (const float*)d_in[3];
    float* out   = (float*)d_out;
    float* p_out = out + (size_t)B_ * T_ * 1024;   // concat order: output, then p

    dim3 grid(B_ * (T_ / BT));
    attn_cell_kernel<<<grid, 256, 0, stream>>>(symbols, encodings, M, C, out, p_out);
}